// Round 13
// baseline (170.548 us; speedup 1.0000x reference)
//
#include <hip/hip_runtime.h>
#include <hip/hip_bf16.h>

// SparseNoisyMoE: B=8192, IN=512, OUT=720, E=16, K=2, MOE_TEMP=1.0 (eval mode)
// R13: revert R12 (direct-Wg dot regressed: 512 scalar VMEM loads/thread beat the
// occupancy-round saving it bought). Back to R11's staged-sWg gate, ONE change:
// gate blocks widened 16 -> 64 rows (512 -> 128 gate blocks). Wg staging traffic
// amortized 4x (16.9 -> 4.2MB), 384 fewer block latency chains, 4 independent
// dot chains per thread. Rank bitfield -> 7-bit positions (both sides updated);
// moe self-scan over 128 entries. moe K-loop/epilogue/combine unchanged from R11.

#define BATCH 8192
#define IND   512
#define OUTD  720
#define NEXP  16
#define GBLK  128   // gate blocks (64 rows each)

typedef __attribute__((ext_vector_type(8))) short short8;
typedef __attribute__((ext_vector_type(4))) float floatx4;

__device__ __forceinline__ unsigned short f2bf(float f) {
    union { float f; unsigned u; } v; v.f = f;
    unsigned r = v.u + 0x7FFFu + ((v.u >> 16) & 1u);   // RNE
    return (unsigned short)(r >> 16);
}
__device__ __forceinline__ float bf2f(unsigned short u) {
    union { unsigned u; float f; } v; v.u = ((unsigned)u) << 16;
    return v.f;
}

// async 16B global->LDS (direct-to-shared DMA; LDS dest = wave-uniform base + lane*16)
__device__ __forceinline__ void gl2lds16(const void* g, void* l) {
    __builtin_amdgcn_global_load_lds(
        (const __attribute__((address_space(1))) void*)g,
        (__attribute__((address_space(3))) void*)l, 16, 0, 0);
}

// ---------------- prep: gate (blocks 0..127) + We transpose (blocks 128..3071) ----------------
__global__ __launch_bounds__(256) void prep_kernel(
    const float* __restrict__ x, const float* __restrict__ Wg,
    const float* __restrict__ bg, const float* __restrict__ We,
    float* __restrict__ gates, int* __restrict__ rowinfo,
    unsigned char* __restrict__ cnt8, float* __restrict__ Pblk, float* __restrict__ Dblk,
    unsigned short* __restrict__ xb, unsigned short* __restrict__ Wt)
{
    __shared__ __align__(16) char smem[38400];
    int tid = threadIdx.x;

    if (blockIdx.x < GBLK) {
        // ======== gate: 64 rows per block ========
        float* sWg   = (float*)smem;            // 16*516 fp32 = 33KB (transposed Wg)
        float* sg    = sWg + 16 * 516;          // 64*17
        float* smax  = sg + 64 * 17;            // 64
        float* sinv  = smax + 64;               // 64
        int*   sasgn = (int*)(sinv + 64);       // 64: i0 | i1<<8

        int rbase = blockIdx.x * 64;

        // stage Wg transposed: Wg[i][e] -> sWg[e*516+i]  (once per 64 rows)
        const float4* gw4 = (const float4*)Wg;
        #pragma unroll
        for (int j = 0; j < 8; ++j) {
            int f = tid + j * 256;
            float4 v = gw4[f];
            int i  = f >> 2;
            int e0 = (f & 3) * 4;
            sWg[(e0 + 0) * 516 + i] = v.x;
            sWg[(e0 + 1) * 516 + i] = v.y;
            sWg[(e0 + 2) * 516 + i] = v.z;
            sWg[(e0 + 3) * 516 + i] = v.w;
        }

        // x -> bf16 conversion: 64 rows = 4096 short8 chunks (coalesced; warms L1/L2)
        const float4* gx4 = (const float4*)(x + (size_t)rbase * IND);
        #pragma unroll
        for (int j = 0; j < 16; ++j) {
            int f = tid + j * 256;        // 0..4095: one float4 PAIR each
            float4 v0 = gx4[2 * f];
            float4 v1 = gx4[2 * f + 1];
            short8 o;
            o[0] = (short)f2bf(v0.x); o[1] = (short)f2bf(v0.y);
            o[2] = (short)f2bf(v0.z); o[3] = (short)f2bf(v0.w);
            o[4] = (short)f2bf(v1.x); o[5] = (short)f2bf(v1.y);
            o[6] = (short)f2bf(v1.z); o[7] = (short)f2bf(v1.w);
            *(short8*)&xb[(size_t)rbase * IND + (size_t)f * 8] = o;
        }
        __syncthreads();

        // phase 1: thread (r16,e) does rows c*16+r16, c=0..3 (4 independent chains)
        int r16 = tid >> 4, e = tid & 15;
        const float4* wr = (const float4*)&sWg[e * 516];
        #pragma unroll
        for (int c = 0; c < 4; ++c) {
            int r = c * 16 + r16;
            const float4* xr = (const float4*)(x + (size_t)(rbase + r) * IND);
            float acc = bg[e];
            #pragma unroll 8
            for (int i4 = 0; i4 < 128; ++i4) {
                float4 a = xr[i4], w = wr[i4];
                acc += a.x * w.x + a.y * w.y + a.z * w.z + a.w * w.w;
            }
            sg[r * 17 + e] = acc;   // MOE_TEMP == 1.0
        }
        __syncthreads();

        // phase 2a: one thread per row (tid < 64) -- top-2, gates, softmax denom
        if (tid < 64) {
            int row = rbase + tid;
            float v0 = -1e30f, v1 = -1e30f; int i0 = 0, i1 = 0;
            float g[16];
            #pragma unroll
            for (int ee = 0; ee < 16; ++ee) {
                float v = sg[tid * 17 + ee]; g[ee] = v;
                if (v > v0)      { v1 = v0; i1 = i0; v0 = v; i0 = ee; }
                else if (v > v1) { v1 = v;  i1 = ee; }
            }
            float e1   = expf(v1 - v0);
            float inv2 = 1.f / (1.f + e1);
            gates[row * 2 + 0] = inv2;
            gates[row * 2 + 1] = e1 * inv2;

            float ssum = 0.f;
            #pragma unroll
            for (int ee = 0; ee < 16; ++ee) ssum += expf(g[ee] - v0);
            smax[tid]  = v0;
            sinv[tid]  = 1.f / ssum;
            sasgn[tid] = i0 | (i1 << 8);
        }
        __syncthreads();

        // phase 2b: deterministic ranks (7-bit) + per-block count/D/P (no atomics)
        if (tid < 64) {
            int me  = sasgn[tid];
            int i0  = me & 255, i1 = me >> 8;
            int p0 = 0, p1 = 0;
            for (int rp = 0; rp < tid; ++rp) {
                int a = sasgn[rp];
                int a0 = a & 255, a1 = a >> 8;
                p0 += (a0 == i0) + (a1 == i0);
                p1 += (a0 == i1) + (a1 == i1);
            }
            rowinfo[rbase + tid] = i0 | (i1 << 4) | (p0 << 8) | (p1 << 15);
        }
        if (tid < 16) {
            int ee = tid;
            int cnt = 0; float D = 0.f, P = 0.f;
            #pragma unroll
            for (int rp = 0; rp < 64; ++rp) {
                int a = sasgn[rp];
                int a0 = a & 255, a1 = a >> 8;
                cnt += (a0 == ee) + (a1 == ee);
                D   += (a0 == ee) ? 1.f : 0.f;
                P   += expf(sg[rp * 17 + ee] - smax[rp]) * sinv[rp];
            }
            cnt8[blockIdx.x * 16 + ee] = (unsigned char)cnt;
            Dblk[blockIdx.x * 16 + ee] = D;
            Pblk[blockIdx.x * 16 + ee] = P;
        }
    } else {
        // ======== We[e][k][o] fp32 -> Wt[e][o][k] bf16; 32(o) x 64(k) tiles ========
        float* tile = (float*)smem;    // 32*69 fp32 = 8.8KB
        int t  = blockIdx.x - GBLK;    // 0..2943 = 16 * 8 * 23
        int e  = t / 184;              // 184 = 8*23
        int rem = t - e * 184;
        int kb = (rem / 23) * 64;
        int ob = (rem % 23) * 32;
        const float* src = We + (size_t)e * (IND * OUTD);

        #pragma unroll
        for (int p = 0; p < 2; ++p) {
            int f  = tid + p * 256;    // 0..511
            int kk = f >> 3;           // 0..63
            int o4 = f & 7;
            float4 v = make_float4(0.f, 0.f, 0.f, 0.f);
            if (ob + o4 * 4 < OUTD)
                v = *(const float4*)&src[(size_t)(kb + kk) * OUTD + ob + o4 * 4];
            tile[(o4 * 4 + 0) * 69 + kk] = v.x;
            tile[(o4 * 4 + 1) * 69 + kk] = v.y;
            tile[(o4 * 4 + 2) * 69 + kk] = v.z;
            tile[(o4 * 4 + 3) * 69 + kk] = v.w;
        }
        __syncthreads();

        int o  = tid >> 3;
        int k8 = tid & 7;
        if (ob + o < OUTD) {
            const float* sp = &tile[o * 69 + k8 * 8];
            short8 wv;
            #pragma unroll
            for (int q = 0; q < 8; ++q) wv[q] = (short)f2bf(sp[q]);
            *(short8*)&Wt[(size_t)e * (OUTD * IND) + (size_t)(ob + o) * IND + kb + k8 * 8] = wv;
        }
    }
}

// ---------------- bf16 MFMA expert gather-GEMM with SELF-SCAN: 128M x 96N, BK=64 ----------------
__global__ __launch_bounds__(256, 4) void moe_mfma_kernel(
    const unsigned short* __restrict__ xb, const unsigned short* __restrict__ Wt,
    const float* __restrict__ be,
    const unsigned char* __restrict__ cnt8, const int* __restrict__ rowinfo,
    const float* __restrict__ gates,
    unsigned short* __restrict__ partial)
{
    int e = blockIdx.z;
    int r0 = blockIdx.y * 128;
    int n0 = blockIdx.x * 96;

    __shared__ unsigned short sAB[14336];
    __shared__ unsigned short sbase[129];
    __shared__ int   schunk[16];
    __shared__ int   srow[128];
    __shared__ float sgw[128];
    __shared__ unsigned short sent[128];

    int tid = threadIdx.x;

    // ---- self-scan: prefix over 128 gate-block counts for expert e ----
    if (tid < 128) sbase[tid] = cnt8[tid * 16 + e];
    __syncthreads();
    if (tid < 16) {
        int s = 0;
        #pragma unroll
        for (int j = 0; j < 8; ++j) s += sbase[tid * 8 + j];
        schunk[tid] = s;
    }
    __syncthreads();
    if (tid == 0) {
        int run = 0;
        #pragma unroll
        for (int c = 0; c < 16; ++c) { int s = schunk[c]; schunk[c] = run; run += s; }
        sbase[128] = (unsigned short)run;
    }
    __syncthreads();
    if (tid < 16) {
        int run = schunk[tid];
        #pragma unroll
        for (int j = 0; j < 8; ++j) {
            int c = sbase[tid * 8 + j];
            sbase[tid * 8 + j] = (unsigned short)run;
            run += c;
        }
    }
    __syncthreads();
    int n = sbase[128];
    if (r0 >= n) return;

    // ---- derive this tile's rows: binary search + rank match (7-bit positions) ----
    if (tid < 128) {
        int idx = r0 + tid;
        if (idx < n) {
            int g = 0;
            #pragma unroll
            for (int step = 64; step; step >>= 1)
                if (g + step <= 127 && (int)sbase[g + step] <= idx) g += step;
            int local = idx - (int)sbase[g];
            int row = 0, k = 0;
            for (int r = 0; r < 64; ++r) {
                int info = rowinfo[g * 64 + r];
                int i0 = info & 15, i1 = (info >> 4) & 15;
                int p0 = (info >> 8) & 127, p1 = (info >> 15) & 127;
                if (i0 == e && p0 == local) { row = g * 64 + r; k = 0; }
                if (i1 == e && p1 == local) { row = g * 64 + r; k = 1; }
            }
            srow[tid] = row;
            sgw[tid]  = gates[row * 2 + k];
            sent[tid] = (unsigned short)((row << 1) | k);
        } else { srow[tid] = 0; sgw[tid] = 0.f; sent[tid] = 0; }
    }
    __syncthreads();

    // ---- K-loop ----
    int lane = tid & 63, wave = tid >> 6;
    int lsub = lane >> 3;
    int swz  = (lane & 7) ^ lsub;

    const unsigned short* aglb[4];
    unsigned short* alds[4];
    #pragma unroll
    for (int g = 0; g < 4; ++g) {
        int row = wave * 32 + g * 8 + lsub;
        aglb[g] = xb + (size_t)srow[row] * IND + swz * 8;
        alds[g] = &sAB[(wave * 32 + g * 8) * 64];
    }
    const unsigned short* bglb[3];
    unsigned short* blds[3];
    #pragma unroll
    for (int g = 0; g < 3; ++g) {
        int col = n0 + wave * 24 + g * 8 + lsub;
        if (col >= OUTD) col = 0;
        bglb[g] = Wt + ((size_t)e * OUTD + col) * IND + swz * 8;
        blds[g] = &sAB[8192 + (wave * 24 + g * 8) * 64];
    }

    int l15 = lane & 15, quad = lane >> 4;
    int wm = (wave & 1) * 64, wn = (wave >> 1) * 48;
    int axor = (l15 & 7) * 8;

    floatx4 acc[4][3] = {};

    for (int kt = 0; kt < IND / 64; ++kt) {
        __syncthreads();
        #pragma unroll
        for (int g = 0; g < 4; ++g) gl2lds16(aglb[g] + kt * 64, alds[g]);
        #pragma unroll
        for (int g = 0; g < 3; ++g) gl2lds16(bglb[g] + kt * 64, blds[g]);
        __syncthreads();

        #pragma unroll
        for (int ks = 0; ks < 2; ++ks) {
            int ko = ((ks * 4 + quad) * 8) ^ axor;
            short8 a[4], b[3];
            #pragma unroll
            for (int i = 0; i < 4; ++i) a[i] = *(const short8*)&sAB[(wm + i * 16 + l15) * 64 + ko];
            #pragma unroll
            for (int j = 0; j < 3; ++j) b[j] = *(const short8*)&sAB[8192 + (wn + j * 16 + l15) * 64 + ko];
            #pragma unroll
            for (int i = 0; i < 4; ++i)
                #pragma unroll
                for (int j = 0; j < 3; ++j)
                    acc[i][j] = __builtin_amdgcn_mfma_f32_16x16x32_bf16(a[i], b[j], acc[i][j], 0, 0, 0);
        }
    }

    // ---- epilogue: accs -> bf16 LDS tile -> 16B stores to row-indexed partial ----
    __syncthreads();
    #pragma unroll
    for (int j = 0; j < 3; ++j) {
        int coll = wn + j * 16 + l15;
        int gcol = n0 + coll;
        float bev = (gcol < OUTD) ? be[e * OUTD + gcol] : 0.f;
        #pragma unroll
        for (int i = 0; i < 4; ++i) {
            #pragma unroll
            for (int rr = 0; rr < 4; ++rr) {
                int rowl = wm + i * 16 + quad * 4 + rr;
                sAB[rowl * 104 + coll] = f2bf(sgw[rowl] * (acc[i][j][rr] + bev));
            }
        }
    }
    __syncthreads();

    #pragma unroll
    for (int p = 0; p < 6; ++p) {
        int c    = tid + p * 256;
        int rowl = c / 12;
        int ch   = c - rowl * 12;
        int gcol = n0 + ch * 8;
        if (gcol < OUTD && r0 + rowl < n) {
            *(short8*)&partial[(size_t)sent[rowl] * OUTD + gcol] =
                *(const short8*)&sAB[rowl * 104 + ch * 8];
        }
    }
}

// ---------------- combine: out[b] = partial[2b] + partial[2b+1]; block 0 adds lb_loss ----------------
__global__ __launch_bounds__(256) void combine_kernel(
    const unsigned short* __restrict__ partial,
    const float* __restrict__ Pblk, const float* __restrict__ Dblk,
    float* __restrict__ out)
{
    __shared__ float sredP[256], sredD[256];
    unsigned f = blockIdx.x * 256 + threadIdx.x;   // 0 .. B*180-1 (exact grid)
    unsigned b = f / 180u;
    unsigned o4 = (f - b * 180u) * 4u;
    const unsigned short* p0 = partial + (size_t)(2u * b) * OUTD + o4;
    ushort4 u0 = *(const ushort4*)p0;
    ushort4 u1 = *(const ushort4*)(p0 + OUTD);
    float4 rv;
    rv.x = bf2f(u0.x) + bf2f(u1.x);
    rv.y = bf2f(u0.y) + bf2f(u1.y);
    rv.z = bf2f(u0.z) + bf2f(u1.z);
    rv.w = bf2f(u0.w) + bf2f(u1.w);
    *(float4*)(out + (size_t)b * OUTD + o4) = rv;

    if (blockIdx.x == 0) {
        int tid = threadIdx.x;
        int e = tid & 15, stripe = tid >> 4;
        float accP = 0.f, accD = 0.f;
        #pragma unroll
        for (int j = 0; j < 8; ++j) {
            int g = stripe * 8 + j;
            accP += Pblk[g * 16 + e];
            accD += Dblk[g * 16 + e];
        }
        sredP[tid] = accP; sredD[tid] = accD;
        __syncthreads();
        if (tid == 0) {
            float s = 0.f;
            for (int ee = 0; ee < 16; ++ee) {
                float P = 0.f, D = 0.f;
                #pragma unroll
                for (int st = 0; st < 16; ++st) { P += sredP[st * 16 + ee]; D += sredD[st * 16 + ee]; }
                s += (D / (float)BATCH) * (P / (float)BATCH);
            }
            out[(size_t)BATCH * OUTD] = s * (float)NEXP;
        }
    }
}

extern "C" void kernel_launch(void* const* d_in, const int* in_sizes, int n_in,
                              void* d_out, int out_size, void* d_ws, size_t ws_size,
                              hipStream_t stream)
{
    const float* x  = (const float*)d_in[0];
    const float* Wg = (const float*)d_in[1];
    const float* bg = (const float*)d_in[2];
    const float* We = (const float*)d_in[3];
    const float* be = (const float*)d_in[4];
    float* out = (float*)d_out;

    char* ws = (char*)d_ws;
    float* gates   = (float*)ws;                               // 64 KB
    int*   rowinfo = (int*)(ws + 65536);                       // 32 KB
    unsigned char* cnt8 = (unsigned char*)(ws + 98304);        // 2 KB
    float* Pblk    = (float*)(ws + 106496);                    // 8 KB
    float* Dblk    = (float*)(ws + 139264);                    // 8 KB
    size_t off_xb  = 172032;                                   // 256-aligned
    unsigned short* xb = (unsigned short*)(ws + off_xb);                  // 8.39 MB
    size_t off_wt = off_xb + (size_t)BATCH * IND * 2;
    unsigned short* Wt = (unsigned short*)(ws + off_wt);                  // 11.80 MB
    size_t off_pt = off_wt + (size_t)NEXP * OUTD * IND * 2;
    unsigned short* partial = (unsigned short*)(ws + off_pt);             // 23.6 MB (row-indexed)

    prep_kernel<<<GBLK + 2944, 256, 0, stream>>>(x, Wg, bg, We, gates, rowinfo,
                                                 cnt8, Pblk, Dblk, xb, Wt);

    // grid.y = 10 covers up to 1280 rows/expert (mean 1024, sd ~31 -> 8+ sigma)
    dim3 grid(8, 10, NEXP);
    moe_mfma_kernel<<<grid, 256, 0, stream>>>(xb, Wt, be, cnt8, rowinfo, gates, partial);

    combine_kernel<<<(BATCH * (OUTD / 4)) / 256, 256, 0, stream>>>(partial, Pblk, Dblk, out);
}

// Round 14
// 140.186 us; speedup vs baseline: 1.2166x; 1.2166x over previous
//
#include <hip/hip_runtime.h>
#include <hip/hip_bf16.h>

// SparseNoisyMoE: B=8192, IN=512, OUT=720, E=16, K=2, MOE_TEMP=1.0 (eval mode)
// R14 = exact revert to R11 (proven best: 141.2us). R12 (direct-Wg dot, 8/CU) and
// R13 (64-row gate blocks, union LDS 38.4KB -> 4/CU for all prep) both regressed;
// R10 (split kernels) regressed via node overhead. R11's config is a verified
// local optimum: 3 nodes, staged-sWg 16-row gate fused with transpose, self-scan
// MFMA moe (128Mx96N BK=64, global_load_lds, XOR-swizzled LDS, coalesced bf16
// epilogue), streaming combine.

#define BATCH 8192
#define IND   512
#define OUTD  720
#define NEXP  16
#define NGBLK 512  // gate blocks (16 rows each)

typedef __attribute__((ext_vector_type(8))) short short8;
typedef __attribute__((ext_vector_type(4))) float floatx4;

__device__ __forceinline__ unsigned short f2bf(float f) {
    union { float f; unsigned u; } v; v.f = f;
    unsigned r = v.u + 0x7FFFu + ((v.u >> 16) & 1u);   // RNE
    return (unsigned short)(r >> 16);
}
__device__ __forceinline__ float bf2f(unsigned short u) {
    union { unsigned u; float f; } v; v.u = ((unsigned)u) << 16;
    return v.f;
}

// async 16B global->LDS (direct-to-shared DMA; LDS dest = wave-uniform base + lane*16)
__device__ __forceinline__ void gl2lds16(const void* g, void* l) {
    __builtin_amdgcn_global_load_lds(
        (const __attribute__((address_space(1))) void*)g,
        (__attribute__((address_space(3))) void*)l, 16, 0, 0);
}

// ---------------- prep: gate (blocks 0..511) + We transpose (blocks 512..3455) ----------------
__global__ __launch_bounds__(256) void prep_kernel(
    const float* __restrict__ x, const float* __restrict__ Wg,
    const float* __restrict__ bg, const float* __restrict__ We,
    float* __restrict__ gates, int* __restrict__ rowinfo,
    unsigned char* __restrict__ cnt8, float* __restrict__ Pblk, float* __restrict__ Dblk,
    unsigned short* __restrict__ xb, unsigned short* __restrict__ Wt)
{
    __shared__ __align__(16) char smem[35328];
    int tid = threadIdx.x;

    if (blockIdx.x < NGBLK) {
        // ======== gate: 16 rows per block ========
        float* sWg   = (float*)smem;            // 16*516 fp32 = 33KB (transposed Wg)
        float* sg    = sWg + 16 * 516;          // 16*17
        float* smax  = sg + 16 * 17;            // 16
        float* sinv  = smax + 16;               // 16
        int*   sasgn = (int*)(sinv + 16);       // 16: i0 | i1<<8

        int rbase = blockIdx.x * 16;

        // stage Wg transposed: Wg[i][e] -> sWg[e*516+i]
        const float4* gw4 = (const float4*)Wg;
        #pragma unroll
        for (int j = 0; j < 8; ++j) {
            int f = tid + j * 256;
            float4 v = gw4[f];
            int i  = f >> 2;
            int e0 = (f & 3) * 4;
            sWg[(e0 + 0) * 516 + i] = v.x;
            sWg[(e0 + 1) * 516 + i] = v.y;
            sWg[(e0 + 2) * 516 + i] = v.z;
            sWg[(e0 + 3) * 516 + i] = v.w;
        }

        // x -> bf16 conversion (coalesced; warms L1/L2 for the dot below)
        const float4* gx4 = (const float4*)(x + (size_t)rbase * IND);
        #pragma unroll
        for (int j = 0; j < 4; ++j) {
            int f = tid + j * 256;        // 0..1023: one float4 PAIR each
            float4 v0 = gx4[2 * f];
            float4 v1 = gx4[2 * f + 1];
            short8 o;
            o[0] = (short)f2bf(v0.x); o[1] = (short)f2bf(v0.y);
            o[2] = (short)f2bf(v0.z); o[3] = (short)f2bf(v0.w);
            o[4] = (short)f2bf(v1.x); o[5] = (short)f2bf(v1.y);
            o[6] = (short)f2bf(v1.z); o[7] = (short)f2bf(v1.w);
            *(short8*)&xb[(size_t)rbase * IND + (size_t)f * 8] = o;
        }
        __syncthreads();

        // phase 1: thread (r,e); x via broadcast global loads (L1/L2-hot)
        int r = tid >> 4, e = tid & 15;
        const float4* xr = (const float4*)(x + (size_t)(rbase + r) * IND);
        const float4* wr = (const float4*)&sWg[e * 516];
        float acc = bg[e];
        #pragma unroll 8
        for (int i4 = 0; i4 < 128; ++i4) {
            float4 a = xr[i4], w = wr[i4];
            acc += a.x * w.x + a.y * w.y + a.z * w.z + a.w * w.w;
        }
        sg[r * 17 + e] = acc;   // MOE_TEMP == 1.0
        __syncthreads();

        // phase 2a: one thread per row -- top-2, gates, softmax denom
        if (tid < 16) {
            int row = rbase + tid;
            float v0 = -1e30f, v1 = -1e30f; int i0 = 0, i1 = 0;
            float g[16];
            #pragma unroll
            for (int ee = 0; ee < 16; ++ee) {
                float v = sg[tid * 17 + ee]; g[ee] = v;
                if (v > v0)      { v1 = v0; i1 = i0; v0 = v; i0 = ee; }
                else if (v > v1) { v1 = v;  i1 = ee; }
            }
            float e1   = expf(v1 - v0);
            float inv2 = 1.f / (1.f + e1);
            gates[row * 2 + 0] = inv2;
            gates[row * 2 + 1] = e1 * inv2;

            float ssum = 0.f;
            #pragma unroll
            for (int ee = 0; ee < 16; ++ee) ssum += expf(g[ee] - v0);
            smax[tid]  = v0;
            sinv[tid]  = 1.f / ssum;
            sasgn[tid] = i0 | (i1 << 8);
        }
        __syncthreads();

        // phase 2b: deterministic ranks + per-block count/D/P (no atomics)
        if (tid < 16) {
            int me  = sasgn[tid];
            int i0  = me & 255, i1 = me >> 8;
            int p0 = 0, p1 = 0;
            for (int rp = 0; rp < tid; ++rp) {
                int a = sasgn[rp];
                int a0 = a & 255, a1 = a >> 8;
                p0 += (a0 == i0) + (a1 == i0);
                p1 += (a0 == i1) + (a1 == i1);
            }
            rowinfo[rbase + tid] = i0 | (i1 << 4) | (p0 << 8) | (p1 << 13);

            int ee = tid;
            int cnt = 0; float D = 0.f, P = 0.f;
            #pragma unroll
            for (int rp = 0; rp < 16; ++rp) {
                int a = sasgn[rp];
                int a0 = a & 255, a1 = a >> 8;
                cnt += (a0 == ee) + (a1 == ee);
                D   += (a0 == ee) ? 1.f : 0.f;
                P   += expf(sg[rp * 17 + ee] - smax[rp]) * sinv[rp];
            }
            cnt8[blockIdx.x * 16 + ee] = (unsigned char)cnt;
            Dblk[blockIdx.x * 16 + ee] = D;
            Pblk[blockIdx.x * 16 + ee] = P;
        }
    } else {
        // ======== We[e][k][o] fp32 -> Wt[e][o][k] bf16; 32(o) x 64(k) tiles ========
        float* tile = (float*)smem;    // 32*69 fp32 = 8.8KB
        int t  = blockIdx.x - NGBLK;   // 0..2943 = 16 * 8 * 23
        int e  = t / 184;              // 184 = 8*23
        int rem = t - e * 184;
        int kb = (rem / 23) * 64;
        int ob = (rem % 23) * 32;
        const float* src = We + (size_t)e * (IND * OUTD);

        #pragma unroll
        for (int p = 0; p < 2; ++p) {
            int f  = tid + p * 256;    // 0..511
            int kk = f >> 3;           // 0..63
            int o4 = f & 7;
            float4 v = make_float4(0.f, 0.f, 0.f, 0.f);
            if (ob + o4 * 4 < OUTD)
                v = *(const float4*)&src[(size_t)(kb + kk) * OUTD + ob + o4 * 4];
            tile[(o4 * 4 + 0) * 69 + kk] = v.x;
            tile[(o4 * 4 + 1) * 69 + kk] = v.y;
            tile[(o4 * 4 + 2) * 69 + kk] = v.z;
            tile[(o4 * 4 + 3) * 69 + kk] = v.w;
        }
        __syncthreads();

        int o  = tid >> 3;
        int k8 = tid & 7;
        if (ob + o < OUTD) {
            const float* sp = &tile[o * 69 + k8 * 8];
            short8 wv;
            #pragma unroll
            for (int q = 0; q < 8; ++q) wv[q] = (short)f2bf(sp[q]);
            *(short8*)&Wt[(size_t)e * (OUTD * IND) + (size_t)(ob + o) * IND + kb + k8 * 8] = wv;
        }
    }
}

// ---------------- bf16 MFMA expert gather-GEMM with SELF-SCAN: 128M x 96N, BK=64 ----------------
__global__ __launch_bounds__(256, 4) void moe_mfma_kernel(
    const unsigned short* __restrict__ xb, const unsigned short* __restrict__ Wt,
    const float* __restrict__ be,
    const unsigned char* __restrict__ cnt8, const int* __restrict__ rowinfo,
    const float* __restrict__ gates,
    unsigned short* __restrict__ partial)
{
    int e = blockIdx.z;
    int r0 = blockIdx.y * 128;
    int n0 = blockIdx.x * 96;

    __shared__ unsigned short sAB[14336];
    __shared__ unsigned short sbase[513];
    __shared__ int   schunk[16];
    __shared__ int   srow[128];
    __shared__ float sgw[128];
    __shared__ unsigned short sent[128];

    int tid = threadIdx.x;

    // ---- self-scan: prefix over 512 gate-block counts for expert e ----
    sbase[tid]       = cnt8[tid * 16 + e];
    sbase[tid + 256] = cnt8[(tid + 256) * 16 + e];
    __syncthreads();
    if (tid < 16) {
        int s = 0;
        #pragma unroll
        for (int j = 0; j < 32; ++j) s += sbase[tid * 32 + j];
        schunk[tid] = s;
    }
    __syncthreads();
    if (tid == 0) {
        int run = 0;
        #pragma unroll
        for (int c = 0; c < 16; ++c) { int s = schunk[c]; schunk[c] = run; run += s; }
        sbase[512] = (unsigned short)run;
    }
    __syncthreads();
    if (tid < 16) {
        int run = schunk[tid];
        #pragma unroll
        for (int j = 0; j < 32; ++j) {
            int c = sbase[tid * 32 + j];
            sbase[tid * 32 + j] = (unsigned short)run;
            run += c;
        }
    }
    __syncthreads();
    int n = sbase[512];
    if (r0 >= n) return;

    // ---- derive this tile's rows: binary search + rank match ----
    if (tid < 128) {
        int idx = r0 + tid;
        if (idx < n) {
            int g = 0;
            #pragma unroll
            for (int step = 256; step; step >>= 1)
                if (g + step <= 511 && (int)sbase[g + step] <= idx) g += step;
            int local = idx - (int)sbase[g];
            int row = 0, k = 0;
            #pragma unroll
            for (int r = 0; r < 16; ++r) {
                int info = rowinfo[g * 16 + r];
                int i0 = info & 15, i1 = (info >> 4) & 15;
                int p0 = (info >> 8) & 31, p1 = (info >> 13) & 31;
                if (i0 == e && p0 == local) { row = g * 16 + r; k = 0; }
                if (i1 == e && p1 == local) { row = g * 16 + r; k = 1; }
            }
            srow[tid] = row;
            sgw[tid]  = gates[row * 2 + k];
            sent[tid] = (unsigned short)((row << 1) | k);
        } else { srow[tid] = 0; sgw[tid] = 0.f; sent[tid] = 0; }
    }
    __syncthreads();

    // ---- K-loop ----
    int lane = tid & 63, wave = tid >> 6;
    int lsub = lane >> 3;
    int swz  = (lane & 7) ^ lsub;

    const unsigned short* aglb[4];
    unsigned short* alds[4];
    #pragma unroll
    for (int g = 0; g < 4; ++g) {
        int row = wave * 32 + g * 8 + lsub;
        aglb[g] = xb + (size_t)srow[row] * IND + swz * 8;
        alds[g] = &sAB[(wave * 32 + g * 8) * 64];
    }
    const unsigned short* bglb[3];
    unsigned short* blds[3];
    #pragma unroll
    for (int g = 0; g < 3; ++g) {
        int col = n0 + wave * 24 + g * 8 + lsub;
        if (col >= OUTD) col = 0;
        bglb[g] = Wt + ((size_t)e * OUTD + col) * IND + swz * 8;
        blds[g] = &sAB[8192 + (wave * 24 + g * 8) * 64];
    }

    int l15 = lane & 15, quad = lane >> 4;
    int wm = (wave & 1) * 64, wn = (wave >> 1) * 48;
    int axor = (l15 & 7) * 8;

    floatx4 acc[4][3] = {};

    for (int kt = 0; kt < IND / 64; ++kt) {
        __syncthreads();
        #pragma unroll
        for (int g = 0; g < 4; ++g) gl2lds16(aglb[g] + kt * 64, alds[g]);
        #pragma unroll
        for (int g = 0; g < 3; ++g) gl2lds16(bglb[g] + kt * 64, blds[g]);
        __syncthreads();

        #pragma unroll
        for (int ks = 0; ks < 2; ++ks) {
            int ko = ((ks * 4 + quad) * 8) ^ axor;
            short8 a[4], b[3];
            #pragma unroll
            for (int i = 0; i < 4; ++i) a[i] = *(const short8*)&sAB[(wm + i * 16 + l15) * 64 + ko];
            #pragma unroll
            for (int j = 0; j < 3; ++j) b[j] = *(const short8*)&sAB[8192 + (wn + j * 16 + l15) * 64 + ko];
            #pragma unroll
            for (int i = 0; i < 4; ++i)
                #pragma unroll
                for (int j = 0; j < 3; ++j)
                    acc[i][j] = __builtin_amdgcn_mfma_f32_16x16x32_bf16(a[i], b[j], acc[i][j], 0, 0, 0);
        }
    }

    // ---- epilogue: accs -> bf16 LDS tile -> 16B stores to row-indexed partial ----
    __syncthreads();
    #pragma unroll
    for (int j = 0; j < 3; ++j) {
        int coll = wn + j * 16 + l15;
        int gcol = n0 + coll;
        float bev = (gcol < OUTD) ? be[e * OUTD + gcol] : 0.f;
        #pragma unroll
        for (int i = 0; i < 4; ++i) {
            #pragma unroll
            for (int rr = 0; rr < 4; ++rr) {
                int rowl = wm + i * 16 + quad * 4 + rr;
                sAB[rowl * 104 + coll] = f2bf(sgw[rowl] * (acc[i][j][rr] + bev));
            }
        }
    }
    __syncthreads();

    #pragma unroll
    for (int p = 0; p < 6; ++p) {
        int c    = tid + p * 256;
        int rowl = c / 12;
        int ch   = c - rowl * 12;
        int gcol = n0 + ch * 8;
        if (gcol < OUTD && r0 + rowl < n) {
            *(short8*)&partial[(size_t)sent[rowl] * OUTD + gcol] =
                *(const short8*)&sAB[rowl * 104 + ch * 8];
        }
    }
}

// ---------------- combine: out[b] = partial[2b] + partial[2b+1]; block 0 adds lb_loss ----------------
__global__ __launch_bounds__(256) void combine_kernel(
    const unsigned short* __restrict__ partial,
    const float* __restrict__ Pblk, const float* __restrict__ Dblk,
    float* __restrict__ out)
{
    __shared__ float sredP[256], sredD[256];
    unsigned f = blockIdx.x * 256 + threadIdx.x;   // 0 .. B*180-1 (exact grid)
    unsigned b = f / 180u;
    unsigned o4 = (f - b * 180u) * 4u;
    const unsigned short* p0 = partial + (size_t)(2u * b) * OUTD + o4;
    ushort4 u0 = *(const ushort4*)p0;
    ushort4 u1 = *(const ushort4*)(p0 + OUTD);
    float4 rv;
    rv.x = bf2f(u0.x) + bf2f(u1.x);
    rv.y = bf2f(u0.y) + bf2f(u1.y);
    rv.z = bf2f(u0.z) + bf2f(u1.z);
    rv.w = bf2f(u0.w) + bf2f(u1.w);
    *(float4*)(out + (size_t)b * OUTD + o4) = rv;

    if (blockIdx.x == 0) {
        int tid = threadIdx.x;
        int e = tid & 15, stripe = tid >> 4;
        float accP = 0.f, accD = 0.f;
        for (int j = 0; j < 32; ++j) {
            int g = stripe * 32 + j;
            accP += Pblk[g * 16 + e];
            accD += Dblk[g * 16 + e];
        }
        sredP[tid] = accP; sredD[tid] = accD;
        __syncthreads();
        if (tid == 0) {
            float s = 0.f;
            for (int ee = 0; ee < 16; ++ee) {
                float P = 0.f, D = 0.f;
                #pragma unroll
                for (int st = 0; st < 16; ++st) { P += sredP[st * 16 + ee]; D += sredD[st * 16 + ee]; }
                s += (D / (float)BATCH) * (P / (float)BATCH);
            }
            out[(size_t)BATCH * OUTD] = s * (float)NEXP;
        }
    }
}

extern "C" void kernel_launch(void* const* d_in, const int* in_sizes, int n_in,
                              void* d_out, int out_size, void* d_ws, size_t ws_size,
                              hipStream_t stream)
{
    const float* x  = (const float*)d_in[0];
    const float* Wg = (const float*)d_in[1];
    const float* bg = (const float*)d_in[2];
    const float* We = (const float*)d_in[3];
    const float* be = (const float*)d_in[4];
    float* out = (float*)d_out;

    char* ws = (char*)d_ws;
    float* gates   = (float*)ws;                               // 64 KB
    int*   rowinfo = (int*)(ws + 65536);                       // 32 KB
    unsigned char* cnt8 = (unsigned char*)(ws + 98304);        // 8 KB
    float* Pblk    = (float*)(ws + 106496);                    // 32 KB
    float* Dblk    = (float*)(ws + 139264);                    // 32 KB
    size_t off_xb  = 172032;                                   // 256-aligned
    unsigned short* xb = (unsigned short*)(ws + off_xb);                  // 8.39 MB
    size_t off_wt = off_xb + (size_t)BATCH * IND * 2;
    unsigned short* Wt = (unsigned short*)(ws + off_wt);                  // 11.80 MB
    size_t off_pt = off_wt + (size_t)NEXP * OUTD * IND * 2;
    unsigned short* partial = (unsigned short*)(ws + off_pt);             // 23.6 MB (row-indexed)

    prep_kernel<<<NGBLK + 2944, 256, 0, stream>>>(x, Wg, bg, We, gates, rowinfo,
                                                  cnt8, Pblk, Dblk, xb, Wt);

    // grid.y = 10 covers up to 1280 rows/expert (mean 1024, sd ~31 -> 8+ sigma)
    dim3 grid(8, 10, NEXP);
    moe_mfma_kernel<<<grid, 256, 0, stream>>>(xb, Wt, be, cnt8, rowinfo, gates, partial);

    combine_kernel<<<(BATCH * (OUTD / 4)) / 256, 256, 0, stream>>>(partial, Pblk, Dblk, out);
}